// Round 5
// baseline (461.091 us; speedup 1.0000x reference)
//
#include <hip/hip_runtime.h>
#include <math.h>

#define EMB_D 64
#define MARGIN 2.0e-5f

// ---------------------------------------------------------------------------
// Kernel 1: wsq[k] = numpy-emulated fp32 sum(w_k^2)  (+ zero the suspect ctr).
// numpy pairwise_sum n=64: 8 accumulators r[j]=sum_t a[j+8t], then
// ((r0+r1)+(r2+r3)) + ((r4+r5)+(r6+r7)).   [unchanged from round 3 — proven]
// ---------------------------------------------------------------------------
__global__ __launch_bounds__(256)
void vq_wsq_kernel(const float* __restrict__ w, float* __restrict__ wsq,
                   int* __restrict__ scount, int K) {
    if (blockIdx.x == 0 && threadIdx.x == 0) scount[0] = 0;
    int k = blockIdx.x * 256 + threadIdx.x;
    if (k >= K) return;
    const float* wr = w + (size_t)k * EMB_D;
    float r[8];
#pragma unroll
    for (int j = 0; j < 8; ++j) r[j] = __fmul_rn(wr[j], wr[j]);
#pragma unroll
    for (int t = 1; t < 8; ++t)
#pragma unroll
        for (int j = 0; j < 8; ++j)
            r[j] = __fadd_rn(r[j], __fmul_rn(wr[t * 8 + j], wr[t * 8 + j]));
    float a = __fadd_rn(__fadd_rn(r[0], r[1]), __fadd_rn(r[2], r[3]));
    float b = __fadd_rn(__fadd_rn(r[4], r[5]), __fadd_rn(r[6], r[7]));
    wsq[k] = __fadd_rn(a, b);
}

// ---------------------------------------------------------------------------
// Kernel 2: fp32 SCREEN.  [unchanged from round 3 — proven]
// lane=row, wave=ascending k-chunk; top-2 of s = wsq[k] - 2*x.w; rows with
// s2-s1 <= MARGIN go to the suspect list.
// ---------------------------------------------------------------------------
__global__ __launch_bounds__(256, 4)
void vq_screen_kernel(const float* __restrict__ x, const float* __restrict__ w,
                      const float* __restrict__ wsq, int* __restrict__ fidx,
                      int* __restrict__ slist, int* __restrict__ scount,
                      int K, int N) {
    const int tid  = threadIdx.x;
    const int lane = tid & 63;
    const int wave = tid >> 6;
    const int row  = blockIdx.x * 64 + lane;

    const float4* xrow4 = (const float4*)(x + (size_t)row * EMB_D);
    float xr[EMB_D];
#pragma unroll
    for (int i = 0; i < EMB_D / 4; ++i) {
        float4 v = xrow4[i];
        xr[4 * i + 0] = v.x; xr[4 * i + 1] = v.y;
        xr[4 * i + 2] = v.z; xr[4 * i + 3] = v.w;
    }

    const int kchunk = K >> 2;
    const int kbase  = __builtin_amdgcn_readfirstlane(wave * kchunk);

    float s1 = INFINITY, s2 = INFINITY;
    int   k1 = kbase;
    for (int j = 0; j < kchunk; ++j) {
        const int k = kbase + j;                    // wave-uniform -> s_load
        const float* wr = w + (size_t)k * EMB_D;
        float a0 = 0.f, a1 = 0.f, a2 = 0.f, a3 = 0.f;
#pragma unroll
        for (int i = 0; i < EMB_D; i += 4) {
            a0 = fmaf(xr[i + 0], wr[i + 0], a0);
            a1 = fmaf(xr[i + 1], wr[i + 1], a1);
            a2 = fmaf(xr[i + 2], wr[i + 2], a2);
            a3 = fmaf(xr[i + 3], wr[i + 3], a3);
        }
        const float dot = (a0 + a1) + (a2 + a3);
        const float s   = fmaf(-2.0f, dot, wsq[k]);
        if (s < s1)      { s2 = s1; s1 = s; k1 = k; }  // strict <: first-min
        else if (s < s2) { s2 = s; }
    }

    __shared__ float L1[4][64], L2[4][64];
    __shared__ int   LI[4][64];
    L1[wave][lane] = s1; L2[wave][lane] = s2; LI[wave][lane] = k1;
    __syncthreads();
    if (wave == 0) {
        float g1 = L1[0][lane], g2 = L2[0][lane];
        int   gk = LI[0][lane];
#pragma unroll
        for (int c = 1; c < 4; ++c) {
            float a = L1[c][lane], b = L2[c][lane];
            int   ak = LI[c][lane];
            if (a < g1) { g2 = fminf(g1, b); g1 = a; gk = ak; }
            else        { g2 = fminf(g2, a); }
        }
        fidx[row] = gk;
        if (g2 - g1 <= MARGIN) {          // includes exact ties
            int p = atomicAdd(scount, 1);
            slist[p] = row;
        }
    }
}

// ---------------------------------------------------------------------------
// Kernel 3: exact RESCORE — round-3 proven structure (tile of 64 suspect
// rows; lane=row, wave=ascending k-chunk; f64 dot -> f32 cast -> numpy
// rounding chain; ascending-chunk strict-< argmin combine).
// ONLY change vs round 3: no f64 copy of the x row (inline (double) casts,
// bit-identical math) — removes the 192-VGPR live set that spilled to
// scratch and made each k-iter ~2900 cycles.
// ---------------------------------------------------------------------------
__global__ __launch_bounds__(256, 2)
void vq_rescore_kernel(const float* __restrict__ x, const float* __restrict__ w,
                       const float* __restrict__ wsq, int* __restrict__ fidx,
                       const int* __restrict__ slist,
                       const int* __restrict__ scount, int K, int N) {
    const int tid  = threadIdx.x;
    const int lane = tid & 63;
    const int wave = tid >> 6;
    const int cnt  = scount[0];

    __shared__ float lbest[4][64];
    __shared__ int   lidx[4][64];

    for (int tile = blockIdx.x; tile * 64 < cnt; tile += gridDim.x) {
        const int  li    = tile * 64 + lane;
        const bool valid = li < cnt;
        const int  row   = valid ? slist[li] : 0;

        const float4* xrow4 = (const float4*)(x + (size_t)row * EMB_D);
        float xr[EMB_D];
#pragma unroll
        for (int i = 0; i < EMB_D / 4; ++i) {
            float4 v = xrow4[i];
            xr[4 * i + 0] = v.x; xr[4 * i + 1] = v.y;
            xr[4 * i + 2] = v.z; xr[4 * i + 3] = v.w;
        }
        // numpy-emulated fp32 x_sq
        float r[8];
#pragma unroll
        for (int j = 0; j < 8; ++j) r[j] = __fmul_rn(xr[j], xr[j]);
#pragma unroll
        for (int t = 1; t < 8; ++t)
#pragma unroll
            for (int j = 0; j < 8; ++j)
                r[j] = __fadd_rn(r[j], __fmul_rn(xr[t * 8 + j], xr[t * 8 + j]));
        const float xsq = __fadd_rn(
            __fadd_rn(__fadd_rn(r[0], r[1]), __fadd_rn(r[2], r[3])),
            __fadd_rn(__fadd_rn(r[4], r[5]), __fadd_rn(r[6], r[7])));

        const int kchunk = K >> 2;
        const int kbase  = __builtin_amdgcn_readfirstlane(wave * kchunk);
        float best = INFINITY;
        int   bidx = 0;
        for (int j = 0; j < kchunk; ++j) {
            const int k = kbase + j;
            const float* wr = w + (size_t)k * EMB_D;   // uniform -> s_load
            double a0 = 0.0, a1 = 0.0, a2 = 0.0, a3 = 0.0;
#pragma unroll
            for (int i = 0; i < EMB_D; i += 4) {
                a0 = fma((double)xr[i + 0], (double)wr[i + 0], a0);
                a1 = fma((double)xr[i + 1], (double)wr[i + 1], a1);
                a2 = fma((double)xr[i + 2], (double)wr[i + 2], a2);
                a3 = fma((double)xr[i + 3], (double)wr[i + 3], a3);
            }
            const float mf = (float)((a0 + a1) + (a2 + a3));
            const float t2 = __fsub_rn(xsq, __fmul_rn(2.0f, mf));
            const float sc = __fadd_rn(t2, wsq[k]);
            if (sc < best) { best = sc; bidx = k; }
        }

        lbest[wave][lane] = best;
        lidx[wave][lane]  = bidx;
        __syncthreads();
        if (wave == 0 && valid) {
            float b  = lbest[0][lane];
            int   bi = lidx[0][lane];
#pragma unroll
            for (int c = 1; c < 4; ++c) {
                float v = lbest[c][lane];
                if (v < b) { b = v; bi = lidx[c][lane]; }
            }
            fidx[row] = bi;
        }
        __syncthreads();   // protect LDS reuse next tile
    }
}

// ---------------------------------------------------------------------------
// Kernel 4: gather/write quantized + indices + per-block loss partials.
// [unchanged from round 3 — proven]
// ---------------------------------------------------------------------------
__global__ __launch_bounds__(256)
void vq_gather_kernel(const float* __restrict__ x, const float* __restrict__ w,
                      const int* __restrict__ fidx, float* __restrict__ out,
                      float* __restrict__ blockloss, int N) {
    const int tid  = threadIdx.x;
    const int lane = tid & 63;
    const int wave = tid >> 6;
    __shared__ int kf[64];
    if (tid < 64) {
        int row = blockIdx.x * 64 + tid;
        int k = fidx[row];
        kf[tid] = k;
        out[(size_t)N * EMB_D + row] = (float)k;   // indices chunk as f32
    }
    __syncthreads();

    float lpart = 0.f;
#pragma unroll
    for (int rep = 0; rep < 4; ++rep) {
        int f4   = rep * 256 + tid;
        int rr   = f4 >> 4;
        int c    = f4 & 15;
        int k    = kf[rr];
        int grow = blockIdx.x * 64 + rr;
        float4 wv = ((const float4*)(w + (size_t)k * EMB_D))[c];
        float4 xq = ((const float4*)(x + (size_t)grow * EMB_D))[c];
        ((float4*)out)[(size_t)grow * (EMB_D / 4) + c] = wv;
        float dx = wv.x - xq.x, dy = wv.y - xq.y;
        float dz = wv.z - xq.z, dw = wv.w - xq.w;
        lpart += dx * dx + dy * dy + dz * dz + dw * dw;
    }
#pragma unroll
    for (int off = 32; off > 0; off >>= 1) lpart += __shfl_down(lpart, off);
    __shared__ float lred[4];
    if (lane == 0) lred[wave] = lpart;
    __syncthreads();
    if (tid == 0)
        blockloss[blockIdx.x] = (lred[0] + lred[1]) + (lred[2] + lred[3]);
}

// ---------------------------------------------------------------------------
// Kernel 5: loss = 1.25 * mean((q - x)^2)   [unchanged]
// ---------------------------------------------------------------------------
__global__ __launch_bounds__(256)
void vq_loss_kernel(const float* __restrict__ part, int nb,
                    float* __restrict__ out_loss, float scale) {
    float s = 0.f;
    for (int i = threadIdx.x; i < nb; i += 256) s += part[i];
#pragma unroll
    for (int off = 32; off > 0; off >>= 1) s += __shfl_down(s, off);
    __shared__ float red[4];
    int lane = threadIdx.x & 63, wave = threadIdx.x >> 6;
    if (lane == 0) red[wave] = s;
    __syncthreads();
    if (threadIdx.x == 0)
        out_loss[0] = ((red[0] + red[1]) + (red[2] + red[3])) * scale;
}

extern "C" void kernel_launch(void* const* d_in, const int* in_sizes, int n_in,
                              void* d_out, int out_size, void* d_ws, size_t ws_size,
                              hipStream_t stream) {
    const float* x = (const float*)d_in[0];
    const float* w = (const float*)d_in[1];
    float* out = (float*)d_out;
    const int xsz = in_sizes[0];   // N * D
    const int wsz = in_sizes[1];   // K * D
    const int N   = xsz / EMB_D;   // 65536
    const int K   = wsz / EMB_D;   // 1024
    const int NB  = N / 64;        // 1024

    // ws layout: [scount:64 int][slist:N int][fidx:N int][wsq:K f][blockloss:NB f]
    int*   scount    = (int*)d_ws;
    int*   slist     = scount + 64;
    int*   fidx      = slist + N;
    float* wsq       = (float*)(fidx + N);
    float* blockloss = wsq + K;

    vq_wsq_kernel<<<(K + 255) / 256, 256, 0, stream>>>(w, wsq, scount, K);
    vq_screen_kernel<<<NB, 256, 0, stream>>>(x, w, wsq, fidx, slist, scount, K, N);
    vq_rescore_kernel<<<256, 256, 0, stream>>>(x, w, wsq, fidx, slist, scount, K, N);
    vq_gather_kernel<<<NB, 256, 0, stream>>>(x, w, fidx, out, blockloss, N);
    vq_loss_kernel<<<1, 256, 0, stream>>>(blockloss, NB,
                                          out + (size_t)N * EMB_D + N,
                                          1.25f / (float)xsz);
}